// Round 19
// baseline (177.956 us; speedup 1.0000x reference)
//
#include <hip/hip_runtime.h>

#define NN 100000      // nodes
#define NE 1600000     // edges
#define NF 128         // in features
#define NH 64          // hidden
#define NC 40          // classes

#define BKN 128                      // nodes per bucket
#define NBK ((NN + BKN - 1) / BKN)   // 782 buckets
#define CH  4096                     // edges per scatter block
#define NCHB ((NE + CH - 1) / CH)    // 391 scatter blocks
#define CAPB 2560                    // slots per bucket region (mean 2046, sigma 45)
#define OFFS (BKN + 1)
#define HCAP 1408                    // max edges per 64-node half-bucket (mean 1023, +12 sigma)
#define XTS 68                       // gemm1 X row stride in uints (136 bf16)

typedef short bf16x8 __attribute__((ext_vector_type(8)));
typedef float f32x4  __attribute__((ext_vector_type(4)));
typedef unsigned int u32x4 __attribute__((ext_vector_type(4)));

__device__ __forceinline__ unsigned short f2bf(float f) {
    unsigned int u = __builtin_bit_cast(unsigned int, f);
    u += 0x7FFFu + ((u >> 16) & 1u);          // round-to-nearest-even
    return (unsigned short)(u >> 16);
}
__device__ __forceinline__ float bfl(unsigned int u) {
    return __builtin_bit_cast(float, u << 16);
}
__device__ __forceinline__ float bfh(unsigned int u) {
    return __builtin_bit_cast(float, u & 0xFFFF0000u);
}
__device__ __forceinline__ unsigned int pk2(float a, float b) {
    return (unsigned int)f2bf(a) | ((unsigned int)f2bf(b) << 16);
}
// accumulate 8 bf16 (one uint4 = 16B) into lo{f0,f2,f4,f6} / hi{f1,f3,f5,f7}
__device__ __forceinline__ void bacc8(float4& lo, float4& hi, uint4 v) {
    lo.x += bfl(v.x); hi.x += bfh(v.x);
    lo.y += bfl(v.y); hi.y += bfh(v.y);
    lo.z += bfl(v.z); hi.z += bfh(v.z);
    lo.w += bfl(v.w); hi.w += bfh(v.w);
}
// sc0 (GLC) load: volatile lowers to L1-bypass global_load on CDNA
__device__ __forceinline__ uint4 ldv(const uint4* p) {
    u32x4 v = *(const volatile u32x4*)p;
    return __builtin_bit_cast(uint4, v);
}

// prep: zero gcnt + transpose all weights to bf16 col-major
__global__ __launch_bounds__(256) void prep_wt(const float* __restrict__ W1,
                                               const float* __restrict__ W2,
                                               const float* __restrict__ Wc,
                                               unsigned short* __restrict__ Wt1,
                                               unsigned short* __restrict__ Wt2,
                                               unsigned short* __restrict__ Wtc,
                                               int* __restrict__ gcnt) {
    int t = blockIdx.x * 256 + threadIdx.x;
    if (t < 8192) {                               // 64 x 128
        int j = t >> 7, k = t & 127;
        Wt1[j * 128 + k] = f2bf(W1[k * 64 + j]);
    } else if (t < 8192 + 4096) {                 // 64 x 64
        int u = t - 8192;
        int j = u >> 6, k = u & 63;
        Wt2[j * 64 + k] = f2bf(W2[k * 64 + j]);
    } else if (t < 8192 + 4096 + 3072) {          // 48 x 64
        int u = t - 8192 - 4096;
        int j = u >> 6, k = u & 63;
        Wtc[j * 64 + k] = (j < NC) ? f2bf(Wc[k * NC + j]) : (unsigned short)0;
    } else if (t < 8192 + 4096 + 3072 + NBK) {
        gcnt[t - 8192 - 4096 - 3072] = 0;
    }
}

// ---------------- fused: bucket_scatter (blocks < NCHB) | gemm1 (rest) ----------------
// Independent work overlapped in one launch. gemm1 emits UNSCALED bf16 x@W1
// (dinv not ready yet); csr_sort applies dinv in place afterwards.
// enc = (col & 127) << 24 | row      (row < 2^17)
__global__ __launch_bounds__(256) void scatter_gemm1(const int* __restrict__ row,
                                                     const int* __restrict__ col,
                                                     int* __restrict__ gcnt,
                                                     unsigned int* __restrict__ encs,
                                                     const float* __restrict__ x,
                                                     const unsigned short* __restrict__ Wt1,
                                                     unsigned short* __restrict__ hsb) {
    __shared__ __align__(16) char smem[37120];
    int tid = threadIdx.x;
    if (blockIdx.x < NCHB) {
        // ---- scatter body ----
        int* h     = (int*)smem;                           // NBK ints
        int* loff  = (int*)(smem + 3136);
        int* cur   = (int*)(smem + 6272);
        int* gbase = (int*)(smem + 9408);
        unsigned int*   stage = (unsigned int*)(smem + 12544);   // CH
        unsigned short* sbkt  = (unsigned short*)(smem + 28928); // CH
        for (int i = tid; i < NBK; i += 256) h[i] = 0;
        __syncthreads();
        int e0 = blockIdx.x * CH;
        int nval = NE - e0; if (nval > CH) nval = CH;
        int c[16];
        #pragma unroll
        for (int i = 0; i < 16; ++i) {
            int e = e0 + i * 256 + tid;
            c[i] = (e < NE) ? col[e] : -1;
            if (c[i] >= 0) atomicAdd(&h[c[i] >> 7], 1);
        }
        __syncthreads();
        // exclusive scan of h[0..NBK) by wave 0 (13 elems/lane)
        if (tid < 64) {
            int lane = tid, base = lane * 13;
            int pre[13]; int sum = 0;
            #pragma unroll
            for (int j = 0; j < 13; ++j) {
                int idx = base + j;
                int xx = (idx < NBK) ? h[idx] : 0;
                pre[j] = sum; sum += xx;
            }
            int run = sum;
            #pragma unroll
            for (int d = 1; d < 64; d <<= 1) {
                int n = __shfl_up(run, d, 64);
                if (lane >= d) run += n;
            }
            int lex = run - sum;
            #pragma unroll
            for (int j = 0; j < 13; ++j) {
                int idx = base + j;
                if (idx < NBK) { loff[idx] = lex + pre[j]; cur[idx] = lex + pre[j]; }
            }
        }
        __syncthreads();
        for (int i = tid; i < NBK; i += 256) {
            int cnt = h[i];
            gbase[i] = cnt ? atomicAdd(&gcnt[i], cnt) : 0;
        }
        __syncthreads();
        #pragma unroll
        for (int i = 0; i < 16; ++i) {
            int e = e0 + i * 256 + tid;
            if (e < NE) {
                int cc = c[i], b = cc >> 7;
                int r = atomicAdd(&cur[b], 1);
                stage[r] = ((unsigned int)(cc & 127) << 24) | (unsigned int)row[e];
                sbkt[r] = (unsigned short)b;
            }
        }
        __syncthreads();
        for (int s = tid; s < nval; s += 256) {
            int b = sbkt[s];
            encs[(size_t)b * CAPB + gbase[b] + (s - loff[b])] = stage[s];
        }
    } else {
        // ---- gemm1 body (unscaled) ----
        unsigned int* Xl = (unsigned int*)smem;            // 64*XTS uints
        int rbase = (blockIdx.x - NCHB) * 64;
        #pragma unroll
        for (int p = 0; p < 8; ++p) {
            int fid = p * 256 + tid;                       // 0..2047 float4s
            int m = fid >> 5, c4 = fid & 31;
            int rr = rbase + m; if (rr >= NN) rr = NN - 1;
            float4 v = *(const float4*)(x + (size_t)rr * NF + c4 * 4);
            uint2 u;
            u.x = pk2(v.x, v.y);
            u.y = pk2(v.z, v.w);
            *(uint2*)&Xl[m * XTS + c4 * 2] = u;
        }
        __syncthreads();
        int wid = tid >> 6, lane = tid & 63;
        int lm = lane & 15, lg = lane >> 4;
        bf16x8 af[4];
        #pragma unroll
        for (int kh = 0; kh < 4; ++kh)
            af[kh] = __builtin_bit_cast(bf16x8,
                        *(const uint4*)&Xl[(wid * 16 + lm) * XTS + kh * 16 + lg * 4]);
        f32x4 acc[4];
        #pragma unroll
        for (int ct = 0; ct < 4; ++ct) {
            acc[ct] = (f32x4){0.f, 0.f, 0.f, 0.f};
            #pragma unroll
            for (int kh = 0; kh < 4; ++kh) {
                bf16x8 bf = __builtin_bit_cast(bf16x8,
                    *(const uint4*)(Wt1 + (size_t)(ct * 16 + lm) * 128 + kh * 32 + lg * 8));
                acc[ct] = __builtin_amdgcn_mfma_f32_16x16x32_bf16(af[kh], bf, acc[ct], 0, 0, 0);
            }
        }
        #pragma unroll
        for (int ct = 0; ct < 4; ++ct) {
            #pragma unroll
            for (int rg = 0; rg < 4; ++rg) {
                int rloc = wid * 16 + lg * 4 + rg;
                int r = rbase + rloc;
                if (r < NN)
                    hsb[(size_t)r * NH + ct * 16 + lm] = f2bf(acc[ct][rg]);
            }
        }
    }
}

// ---------------- csr_sort: node-sort bucket IN PLACE, emit off + dinv, ----------------
// and apply dinv to the bucket's 128 rows of tab (bf16) in place.
__global__ __launch_bounds__(256) void csr_sort(unsigned int* __restrict__ encs,
                                                const int* __restrict__ gcnt,
                                                int* __restrict__ offg,
                                                float* __restrict__ dinv,
                                                unsigned int* __restrict__ tab) {
    __shared__ unsigned int sseg[CAPB];
    __shared__ int h[BKN];
    __shared__ int off[OFFS];
    __shared__ int cur[BKN];
    int b = blockIdx.x, tid = threadIdx.x;
    if (tid < BKN) h[tid] = 0;
    __syncthreads();
    int m = gcnt[b];
    unsigned int* seg = encs + (size_t)b * CAPB;
    for (int s = tid; s < m; s += 256) {
        unsigned int e = seg[s];
        sseg[s] = e;
        atomicAdd(&h[e >> 24], 1);
    }
    __syncthreads();
    if (tid < BKN) {
        int g = b * BKN + tid;
        if (g < NN) dinv[g] = rsqrtf((float)(h[tid] + 1));   // +1 self loop
    }
    if (tid < 64) {
        int lane = tid;
        int x0 = h[lane * 2], x1 = h[lane * 2 + 1];
        int sum = x0 + x1, run = sum;
        #pragma unroll
        for (int d = 1; d < 64; d <<= 1) {
            int n = __shfl_up(run, d, 64);
            if (lane >= d) run += n;
        }
        int ex = run - sum;
        off[lane * 2] = ex;          cur[lane * 2] = ex;
        off[lane * 2 + 1] = ex + x0; cur[lane * 2 + 1] = ex + x0;
        if (lane == 63) off[BKN] = run;
    }
    __syncthreads();
    for (int s = tid; s < m; s += 256) {
        unsigned int e = sseg[s];
        int n = e >> 24;
        int r = atomicAdd(&cur[n], 1);
        seg[r] = e & 0xFFFFFFu;
    }
    if (tid < OFFS) offg[b * OFFS + tid] = off[tid];
    // scale this bucket's rows of tab by dinv (h[] is final after first sync)
    uint4* t4 = (uint4*)tab;
    for (int j = tid; j < BKN * 8; j += 256) {
        int n = j >> 3, q = j & 7;
        int g = b * BKN + n;
        if (g < NN) {
            float d = rsqrtf((float)(h[n] + 1));
            uint4 v = t4[(size_t)g * 8 + q];
            uint4 o;
            o.x = pk2(bfl(v.x) * d, bfh(v.x) * d);
            o.y = pk2(bfl(v.y) * d, bfh(v.y) * d);
            o.z = pk2(bfl(v.z) * d, bfh(v.z) * d);
            o.w = pk2(bfl(v.w) * d, bfh(v.w) * d);
            t4[(size_t)g * 8 + q] = o;
        }
    }
}

// ---------------- fused aggregate + MFMA matmul (512 thr, sc0 gathers) ----------------
// Block = HALF bucket (64 nodes), 512 threads = 64 subgroups of 8 lanes.
// Phase A: subgroup owns node; lane = feature octet (uint4); unroll 8; L1-bypass
//          (volatile/sc0) gathers — table is never L1-reused, keep L2 policy.
// Phase B: MFMA 16x16x32, tile-jobs over 8 waves.
//   FINAL=0 (NCT=4): hsb_out[r][c] = bf16(acc * dinv[r])
//   FINAL=1 (NCT=3): f_out[r][c]   = acc + biasB[c]   (c < 40)
template <int FINAL>
__global__ __launch_bounds__(512) void agg_matmul(const unsigned short* __restrict__ hs,
                                                  const int* __restrict__ srow,
                                                  const int* __restrict__ offg,
                                                  const float* __restrict__ dinv,
                                                  const float* __restrict__ biasA,
                                                  const unsigned short* __restrict__ Wt,
                                                  const float* __restrict__ biasB,
                                                  unsigned short* __restrict__ hsb_out,
                                                  float* __restrict__ f_out) {
    __shared__ int off[65];
    __shared__ int sidx[HCAP];
    __shared__ unsigned int htb[64 * 36];        // packed bf16 tile (stride 36 uints)
    __shared__ float sdinv[64];
    int b = blockIdx.x >> 1, half = blockIdx.x & 1;
    int tid = threadIdx.x;
    int rbase = b * BKN + half * 64;
    if (tid < 65) off[tid] = offg[b * OFFS + half * 64 + tid];
    __syncthreads();
    int e0 = off[0], cnt = off[64] - e0;
    const int* ptr = srow + (size_t)b * CAPB + e0;
    for (int s = tid; s < cnt; s += 512) sidx[s] = ptr[s];
    __syncthreads();

    // ---- phase A: gather (one node per 8-lane subgroup) ----
    int n = tid >> 3, sl = tid & 7;
    int g = rbase + n;
    const uint4* hs8 = (const uint4*)hs;         // row = 8 x uint4 (128 B)
    {
        float d = (g < NN) ? dinv[g] : 0.f;
        if (sl == 0) sdinv[n] = d;
        float4 o0 = {}, o1 = {};
        if (g < NN) {
            float4 lo0 = {}, hi0 = {}, lo1 = {}, hi1 = {};
            float4 lo2 = {}, hi2 = {}, lo3 = {}, hi3 = {};
            bacc8(lo0, hi0, ldv(&hs8[(size_t)g * 8 + sl]));      // self loop
            int e = off[n] - e0, ee = off[n + 1] - e0;
            for (; e + 8 <= ee; e += 8) {
                int r0 = sidx[e + 0], r1 = sidx[e + 1];
                int r2 = sidx[e + 2], r3 = sidx[e + 3];
                int r4 = sidx[e + 4], r5 = sidx[e + 5];
                int r6 = sidx[e + 6], r7 = sidx[e + 7];
                uint4 v0 = ldv(&hs8[(size_t)r0 * 8 + sl]);
                uint4 v1 = ldv(&hs8[(size_t)r1 * 8 + sl]);
                uint4 v2 = ldv(&hs8[(size_t)r2 * 8 + sl]);
                uint4 v3 = ldv(&hs8[(size_t)r3 * 8 + sl]);
                uint4 v4 = ldv(&hs8[(size_t)r4 * 8 + sl]);
                uint4 v5 = ldv(&hs8[(size_t)r5 * 8 + sl]);
                uint4 v6 = ldv(&hs8[(size_t)r6 * 8 + sl]);
                uint4 v7 = ldv(&hs8[(size_t)r7 * 8 + sl]);
                bacc8(lo0, hi0, v0); bacc8(lo1, hi1, v1);
                bacc8(lo2, hi2, v2); bacc8(lo3, hi3, v3);
                bacc8(lo0, hi0, v4); bacc8(lo1, hi1, v5);
                bacc8(lo2, hi2, v6); bacc8(lo3, hi3, v7);
            }
            if (e + 4 <= ee) {
                int r0 = sidx[e + 0], r1 = sidx[e + 1];
                int r2 = sidx[e + 2], r3 = sidx[e + 3];
                uint4 v0 = ldv(&hs8[(size_t)r0 * 8 + sl]);
                uint4 v1 = ldv(&hs8[(size_t)r1 * 8 + sl]);
                uint4 v2 = ldv(&hs8[(size_t)r2 * 8 + sl]);
                uint4 v3 = ldv(&hs8[(size_t)r3 * 8 + sl]);
                bacc8(lo0, hi0, v0); bacc8(lo1, hi1, v1);
                bacc8(lo2, hi2, v2); bacc8(lo3, hi3, v3);
                e += 4;
            }
            for (; e < ee; ++e)
                bacc8(lo0, hi0, ldv(&hs8[(size_t)sidx[e] * 8 + sl]));
            lo0.x += lo1.x + lo2.x + lo3.x;  hi0.x += hi1.x + hi2.x + hi3.x;
            lo0.y += lo1.y + lo2.y + lo3.y;  hi0.y += hi1.y + hi2.y + hi3.y;
            lo0.z += lo1.z + lo2.z + lo3.z;  hi0.z += hi1.z + hi2.z + hi3.z;
            lo0.w += lo1.w + lo2.w + lo3.w;  hi0.w += hi1.w + hi2.w + hi3.w;
            float4 bb0 = ((const float4*)biasA)[sl * 2];
            float4 bb1 = ((const float4*)biasA)[sl * 2 + 1];
            o0.x = fmaxf(fmaf(lo0.x, d, bb0.x), 0.f);
            o0.y = fmaxf(fmaf(hi0.x, d, bb0.y), 0.f);
            o0.z = fmaxf(fmaf(lo0.y, d, bb0.z), 0.f);
            o0.w = fmaxf(fmaf(hi0.y, d, bb0.w), 0.f);
            o1.x = fmaxf(fmaf(lo0.z, d, bb1.x), 0.f);
            o1.y = fmaxf(fmaf(hi0.z, d, bb1.y), 0.f);
            o1.z = fmaxf(fmaf(lo0.w, d, bb1.z), 0.f);
            o1.w = fmaxf(fmaf(hi0.w, d, bb1.w), 0.f);
        }
        uint4 pk;                                // feature pairs 4sl..4sl+3
        pk.x = pk2(o0.x, o0.y);
        pk.y = pk2(o0.z, o0.w);
        pk.z = pk2(o1.x, o1.y);
        pk.w = pk2(o1.z, o1.w);
        *(uint4*)&htb[n * 36 + sl * 4] = pk;
    }
    __syncthreads();

    // ---- phase B: MFMA, tile-jobs over 8 waves ----
    constexpr int NCT = FINAL ? 3 : 4;           // col tiles (48 padded / 64)
    int wid = tid >> 6, lane = tid & 63;
    int lm = lane & 15, lg = lane >> 4;
    int rt = wid >> 1;
    int ct0 = (wid & 1) * 2;
    int ct1 = (ct0 + 2 < NCT) ? ct0 + 2 : NCT;
    bf16x8 afrag[2];
    #pragma unroll
    for (int kh = 0; kh < 2; ++kh) {
        const unsigned int* p = &htb[(rt * 16 + lm) * 36 + kh * 16 + lg * 4];
        afrag[kh] = __builtin_bit_cast(bf16x8, *(const uint4*)p);
    }
    for (int ct = ct0; ct < ct1; ++ct) {
        f32x4 acc = (f32x4){0.f, 0.f, 0.f, 0.f};
        #pragma unroll
        for (int kh = 0; kh < 2; ++kh) {
            const unsigned short* q = Wt + (size_t)(ct * 16 + lm) * 64 + kh * 32 + lg * 8;
            bf16x8 bfrag = __builtin_bit_cast(bf16x8, *(const uint4*)q);
            acc = __builtin_amdgcn_mfma_f32_16x16x32_bf16(afrag[kh], bfrag, acc, 0, 0, 0);
        }
        if (!FINAL) {
            #pragma unroll
            for (int rg = 0; rg < 4; ++rg) {
                int rloc = rt * 16 + lg * 4 + rg;
                int r = rbase + rloc;
                if (r < NN) {
                    float v = acc[rg] * sdinv[rloc];
                    hsb_out[(size_t)r * NH + ct * 16 + lm] = f2bf(v);
                }
            }
        } else {
            int c = ct * 16 + lm;
            if (c < NC) {
                float bb = biasB[c];
                #pragma unroll
                for (int rg = 0; rg < 4; ++rg) {
                    int rloc = rt * 16 + lg * 4 + rg;
                    int r = rbase + rloc;
                    if (r < NN)
                        f_out[(size_t)r * NC + c] = acc[rg] + bb;
                }
            }
        }
    }
}

// ---------------- launch ----------------

extern "C" void kernel_launch(void* const* d_in, const int* in_sizes, int n_in,
                              void* d_out, int out_size, void* d_ws, size_t ws_size,
                              hipStream_t stream) {
    const float* x  = (const float*)d_in[0];
    const int* ei   = (const int*)d_in[1];      // [2, NE]
    const int* row  = ei;
    const int* col  = ei + NE;
    const float* W1 = (const float*)d_in[2];
    const float* b1 = (const float*)d_in[3];
    const float* W2 = (const float*)d_in[4];
    const float* b2 = (const float*)d_in[5];
    const float* Wc = (const float*)d_in[6];
    const float* bc = (const float*)d_in[7];
    float* out = (float*)d_out;

    char* ws = (char*)d_ws;
    size_t off = 0;
    auto alloc = [&](size_t bytes) {
        void* p = ws + off;
        off = (off + bytes + 255) & ~(size_t)255;
        return p;
    };
    int*   gcnt = (int*)alloc((size_t)NBK * 4);
    int*   offg = (int*)alloc((size_t)NBK * OFFS * 4);
    float* dinv = (float*)alloc((size_t)NN * 4);
    unsigned int* encs = (unsigned int*)alloc((size_t)NBK * CAPB * 4);   // 8 MB
    unsigned short* hsb1 = (unsigned short*)alloc((size_t)NN * NH * 2);  // bf16 table L1
    unsigned short* hsb2 = (unsigned short*)alloc((size_t)NN * NH * 2);  // bf16 table L2
    unsigned short* Wt1  = (unsigned short*)alloc((size_t)64 * 128 * 2); // bf16 W1^T
    unsigned short* Wt2  = (unsigned short*)alloc((size_t)64 * 64 * 2);  // bf16 W2^T
    unsigned short* Wtc  = (unsigned short*)alloc((size_t)48 * 64 * 2);  // bf16 Wc^T padded

    const int GB = (NN + 63) / 64;               // 1563

    prep_wt<<<64, 256, 0, stream>>>(W1, W2, Wc, Wt1, Wt2, Wtc, gcnt);
    // scatter (391 blocks) overlapped with unscaled gemm1 (1563 blocks)
    scatter_gemm1<<<NCHB + GB, 256, 0, stream>>>(row, col, gcnt, encs, x, Wt1, hsb1);
    // node-sort buckets + dinv + scale hsb1 rows in place
    csr_sort<<<NBK, 256, 0, stream>>>(encs, gcnt, offg, dinv, (unsigned int*)hsb1);
    // fused: agg(hsb1) -> relu -> @W2*dinv -> hsb2
    agg_matmul<0><<<NBK * 2, 512, 0, stream>>>(hsb1, (const int*)encs, offg, dinv,
                                               b1, Wt2, nullptr, hsb2, nullptr);
    // fused: agg(hsb2) -> relu -> @Wc + bc -> out
    agg_matmul<1><<<NBK * 2, 512, 0, stream>>>(hsb2, (const int*)encs, offg, dinv,
                                               b2, Wtc, bc, nullptr, out);
}

// Round 20
// 138.595 us; speedup vs baseline: 1.2840x; 1.2840x over previous
//
#include <hip/hip_runtime.h>

#define NN 100000      // nodes
#define NE 1600000     // edges
#define NF 128         // in features
#define NH 64          // hidden
#define NC 40          // classes

#define BKN 128                      // nodes per bucket
#define NBK ((NN + BKN - 1) / BKN)   // 782 buckets
#define CH  4096                     // edges per scatter block
#define NCHB ((NE + CH - 1) / CH)    // 391 scatter blocks
#define CAPB 2560                    // slots per bucket region (mean 2046, sigma 45)
#define OFFS (BKN + 1)
#define HCAP 1408                    // max edges per 64-node half-bucket (mean 1023, +12 sigma)
#define XTS 68                       // gemm1 X row stride in uints (136 bf16)

typedef short bf16x8 __attribute__((ext_vector_type(8)));
typedef float f32x4  __attribute__((ext_vector_type(4)));

__device__ __forceinline__ unsigned short f2bf(float f) {
    unsigned int u = __builtin_bit_cast(unsigned int, f);
    u += 0x7FFFu + ((u >> 16) & 1u);          // round-to-nearest-even
    return (unsigned short)(u >> 16);
}
__device__ __forceinline__ float bfl(unsigned int u) {
    return __builtin_bit_cast(float, u << 16);
}
__device__ __forceinline__ float bfh(unsigned int u) {
    return __builtin_bit_cast(float, u & 0xFFFF0000u);
}
__device__ __forceinline__ unsigned int pk2(float a, float b) {
    return (unsigned int)f2bf(a) | ((unsigned int)f2bf(b) << 16);
}
// accumulate 8 bf16 (one uint4 = 16B) into lo{f0,f2,f4,f6} / hi{f1,f3,f5,f7}
__device__ __forceinline__ void bacc8(float4& lo, float4& hi, uint4 v) {
    lo.x += bfl(v.x); hi.x += bfh(v.x);
    lo.y += bfl(v.y); hi.y += bfh(v.y);
    lo.z += bfl(v.z); hi.z += bfh(v.z);
    lo.w += bfl(v.w); hi.w += bfh(v.w);
}

// prep: zero gcnt + transpose all weights to bf16 col-major
__global__ __launch_bounds__(256) void prep_wt(const float* __restrict__ W1,
                                               const float* __restrict__ W2,
                                               const float* __restrict__ Wc,
                                               unsigned short* __restrict__ Wt1,
                                               unsigned short* __restrict__ Wt2,
                                               unsigned short* __restrict__ Wtc,
                                               int* __restrict__ gcnt) {
    int t = blockIdx.x * 256 + threadIdx.x;
    if (t < 8192) {                               // 64 x 128
        int j = t >> 7, k = t & 127;
        Wt1[j * 128 + k] = f2bf(W1[k * 64 + j]);
    } else if (t < 8192 + 4096) {                 // 64 x 64
        int u = t - 8192;
        int j = u >> 6, k = u & 63;
        Wt2[j * 64 + k] = f2bf(W2[k * 64 + j]);
    } else if (t < 8192 + 4096 + 3072) {          // 48 x 64
        int u = t - 8192 - 4096;
        int j = u >> 6, k = u & 63;
        Wtc[j * 64 + k] = (j < NC) ? f2bf(Wc[k * NC + j]) : (unsigned short)0;
    } else if (t < 8192 + 4096 + 3072 + NBK) {
        gcnt[t - 8192 - 4096 - 3072] = 0;
    }
}

// ---------------- fused: bucket_scatter (blocks < NCHB) | gemm1 (rest) ----------------
// Independent work overlapped in one launch. gemm1 emits UNSCALED bf16 x@W1
// (dinv not ready yet); csr_sort applies dinv in place afterwards.
// enc = (col & 127) << 24 | row      (row < 2^17)
__global__ __launch_bounds__(256) void scatter_gemm1(const int* __restrict__ row,
                                                     const int* __restrict__ col,
                                                     int* __restrict__ gcnt,
                                                     unsigned int* __restrict__ encs,
                                                     const float* __restrict__ x,
                                                     const unsigned short* __restrict__ Wt1,
                                                     unsigned short* __restrict__ hsb) {
    __shared__ __align__(16) char smem[37120];
    int tid = threadIdx.x;
    if (blockIdx.x < NCHB) {
        // ---- scatter body ----
        int* h     = (int*)smem;                           // NBK ints
        int* loff  = (int*)(smem + 3136);
        int* cur   = (int*)(smem + 6272);
        int* gbase = (int*)(smem + 9408);
        unsigned int*   stage = (unsigned int*)(smem + 12544);   // CH
        unsigned short* sbkt  = (unsigned short*)(smem + 28928); // CH
        for (int i = tid; i < NBK; i += 256) h[i] = 0;
        __syncthreads();
        int e0 = blockIdx.x * CH;
        int nval = NE - e0; if (nval > CH) nval = CH;
        int c[16];
        #pragma unroll
        for (int i = 0; i < 16; ++i) {
            int e = e0 + i * 256 + tid;
            c[i] = (e < NE) ? col[e] : -1;
            if (c[i] >= 0) atomicAdd(&h[c[i] >> 7], 1);
        }
        __syncthreads();
        // exclusive scan of h[0..NBK) by wave 0 (13 elems/lane)
        if (tid < 64) {
            int lane = tid, base = lane * 13;
            int pre[13]; int sum = 0;
            #pragma unroll
            for (int j = 0; j < 13; ++j) {
                int idx = base + j;
                int xx = (idx < NBK) ? h[idx] : 0;
                pre[j] = sum; sum += xx;
            }
            int run = sum;
            #pragma unroll
            for (int d = 1; d < 64; d <<= 1) {
                int n = __shfl_up(run, d, 64);
                if (lane >= d) run += n;
            }
            int lex = run - sum;
            #pragma unroll
            for (int j = 0; j < 13; ++j) {
                int idx = base + j;
                if (idx < NBK) { loff[idx] = lex + pre[j]; cur[idx] = lex + pre[j]; }
            }
        }
        __syncthreads();
        for (int i = tid; i < NBK; i += 256) {
            int cnt = h[i];
            gbase[i] = cnt ? atomicAdd(&gcnt[i], cnt) : 0;
        }
        __syncthreads();
        #pragma unroll
        for (int i = 0; i < 16; ++i) {
            int e = e0 + i * 256 + tid;
            if (e < NE) {
                int cc = c[i], b = cc >> 7;
                int r = atomicAdd(&cur[b], 1);
                stage[r] = ((unsigned int)(cc & 127) << 24) | (unsigned int)row[e];
                sbkt[r] = (unsigned short)b;
            }
        }
        __syncthreads();
        for (int s = tid; s < nval; s += 256) {
            int b = sbkt[s];
            encs[(size_t)b * CAPB + gbase[b] + (s - loff[b])] = stage[s];
        }
    } else {
        // ---- gemm1 body (unscaled) ----
        unsigned int* Xl = (unsigned int*)smem;            // 64*XTS uints
        int rbase = (blockIdx.x - NCHB) * 64;
        #pragma unroll
        for (int p = 0; p < 8; ++p) {
            int fid = p * 256 + tid;                       // 0..2047 float4s
            int m = fid >> 5, c4 = fid & 31;
            int rr = rbase + m; if (rr >= NN) rr = NN - 1;
            float4 v = *(const float4*)(x + (size_t)rr * NF + c4 * 4);
            uint2 u;
            u.x = pk2(v.x, v.y);
            u.y = pk2(v.z, v.w);
            *(uint2*)&Xl[m * XTS + c4 * 2] = u;
        }
        __syncthreads();
        int wid = tid >> 6, lane = tid & 63;
        int lm = lane & 15, lg = lane >> 4;
        bf16x8 af[4];
        #pragma unroll
        for (int kh = 0; kh < 4; ++kh)
            af[kh] = __builtin_bit_cast(bf16x8,
                        *(const uint4*)&Xl[(wid * 16 + lm) * XTS + kh * 16 + lg * 4]);
        f32x4 acc[4];
        #pragma unroll
        for (int ct = 0; ct < 4; ++ct) {
            acc[ct] = (f32x4){0.f, 0.f, 0.f, 0.f};
            #pragma unroll
            for (int kh = 0; kh < 4; ++kh) {
                bf16x8 bf = __builtin_bit_cast(bf16x8,
                    *(const uint4*)(Wt1 + (size_t)(ct * 16 + lm) * 128 + kh * 32 + lg * 8));
                acc[ct] = __builtin_amdgcn_mfma_f32_16x16x32_bf16(af[kh], bf, acc[ct], 0, 0, 0);
            }
        }
        #pragma unroll
        for (int ct = 0; ct < 4; ++ct) {
            #pragma unroll
            for (int rg = 0; rg < 4; ++rg) {
                int rloc = wid * 16 + lg * 4 + rg;
                int r = rbase + rloc;
                if (r < NN)
                    hsb[(size_t)r * NH + ct * 16 + lm] = f2bf(acc[ct][rg]);
            }
        }
    }
}

// ---------------- csr_sort: node-sort bucket IN PLACE, emit off + dinv, ----------------
// and apply dinv to the bucket's 128 rows of tab (bf16) in place.
__global__ __launch_bounds__(256) void csr_sort(unsigned int* __restrict__ encs,
                                                const int* __restrict__ gcnt,
                                                int* __restrict__ offg,
                                                float* __restrict__ dinv,
                                                unsigned int* __restrict__ tab) {
    __shared__ unsigned int sseg[CAPB];
    __shared__ int h[BKN];
    __shared__ int off[OFFS];
    __shared__ int cur[BKN];
    int b = blockIdx.x, tid = threadIdx.x;
    if (tid < BKN) h[tid] = 0;
    __syncthreads();
    int m = gcnt[b];
    unsigned int* seg = encs + (size_t)b * CAPB;
    for (int s = tid; s < m; s += 256) {
        unsigned int e = seg[s];
        sseg[s] = e;
        atomicAdd(&h[e >> 24], 1);
    }
    __syncthreads();
    if (tid < BKN) {
        int g = b * BKN + tid;
        if (g < NN) dinv[g] = rsqrtf((float)(h[tid] + 1));   // +1 self loop
    }
    if (tid < 64) {
        int lane = tid;
        int x0 = h[lane * 2], x1 = h[lane * 2 + 1];
        int sum = x0 + x1, run = sum;
        #pragma unroll
        for (int d = 1; d < 64; d <<= 1) {
            int n = __shfl_up(run, d, 64);
            if (lane >= d) run += n;
        }
        int ex = run - sum;
        off[lane * 2] = ex;          cur[lane * 2] = ex;
        off[lane * 2 + 1] = ex + x0; cur[lane * 2 + 1] = ex + x0;
        if (lane == 63) off[BKN] = run;
    }
    __syncthreads();
    for (int s = tid; s < m; s += 256) {
        unsigned int e = sseg[s];
        int n = e >> 24;
        int r = atomicAdd(&cur[n], 1);
        seg[r] = e & 0xFFFFFFu;
    }
    if (tid < OFFS) offg[b * OFFS + tid] = off[tid];
    // scale this bucket's rows of tab by dinv (h[] is final after first sync)
    uint4* t4 = (uint4*)tab;
    for (int j = tid; j < BKN * 8; j += 256) {
        int n = j >> 3, q = j & 7;
        int g = b * BKN + n;
        if (g < NN) {
            float d = rsqrtf((float)(h[n] + 1));
            uint4 v = t4[(size_t)g * 8 + q];
            uint4 o;
            o.x = pk2(bfl(v.x) * d, bfh(v.x) * d);
            o.y = pk2(bfl(v.y) * d, bfh(v.y) * d);
            o.z = pk2(bfl(v.z) * d, bfh(v.z) * d);
            o.w = pk2(bfl(v.w) * d, bfh(v.w) * d);
            t4[(size_t)g * 8 + q] = o;
        }
    }
}

// ---------------- fused aggregate + MFMA matmul (512 thr, r18 structure) ----------------
// Block = HALF bucket (64 nodes), 512 threads = 64 subgroups of 8 lanes.
// Phase A: subgroup owns node; lane = feature octet (uint4); unroll 8.
// Phase B: MFMA 16x16x32, tile-jobs over 8 waves.
//   FINAL=0 (NCT=4): hsb_out[r][c] = bf16(acc * dinv[r])
//   FINAL=1 (NCT=3): f_out[r][c]   = acc + biasB[c]   (c < 40)
template <int FINAL>
__global__ __launch_bounds__(512) void agg_matmul(const unsigned short* __restrict__ hs,
                                                  const int* __restrict__ srow,
                                                  const int* __restrict__ offg,
                                                  const float* __restrict__ dinv,
                                                  const float* __restrict__ biasA,
                                                  const unsigned short* __restrict__ Wt,
                                                  const float* __restrict__ biasB,
                                                  unsigned short* __restrict__ hsb_out,
                                                  float* __restrict__ f_out) {
    __shared__ int off[65];
    __shared__ int sidx[HCAP];
    __shared__ unsigned int htb[64 * 36];        // packed bf16 tile (stride 36 uints)
    __shared__ float sdinv[64];
    int b = blockIdx.x >> 1, half = blockIdx.x & 1;
    int tid = threadIdx.x;
    int rbase = b * BKN + half * 64;
    if (tid < 65) off[tid] = offg[b * OFFS + half * 64 + tid];
    __syncthreads();
    int e0 = off[0], cnt = off[64] - e0;
    const int* ptr = srow + (size_t)b * CAPB + e0;
    for (int s = tid; s < cnt; s += 512) sidx[s] = ptr[s];
    __syncthreads();

    // ---- phase A: gather (one node per 8-lane subgroup) ----
    int n = tid >> 3, sl = tid & 7;
    int g = rbase + n;
    const uint4* hs8 = (const uint4*)hs;         // row = 8 x uint4 (128 B)
    {
        float d = (g < NN) ? dinv[g] : 0.f;
        if (sl == 0) sdinv[n] = d;
        float4 o0 = {}, o1 = {};
        if (g < NN) {
            float4 lo0 = {}, hi0 = {}, lo1 = {}, hi1 = {};
            float4 lo2 = {}, hi2 = {}, lo3 = {}, hi3 = {};
            bacc8(lo0, hi0, hs8[(size_t)g * 8 + sl]);      // self loop
            int e = off[n] - e0, ee = off[n + 1] - e0;
            for (; e + 8 <= ee; e += 8) {
                int r0 = sidx[e + 0], r1 = sidx[e + 1];
                int r2 = sidx[e + 2], r3 = sidx[e + 3];
                int r4 = sidx[e + 4], r5 = sidx[e + 5];
                int r6 = sidx[e + 6], r7 = sidx[e + 7];
                uint4 v0 = hs8[(size_t)r0 * 8 + sl];
                uint4 v1 = hs8[(size_t)r1 * 8 + sl];
                uint4 v2 = hs8[(size_t)r2 * 8 + sl];
                uint4 v3 = hs8[(size_t)r3 * 8 + sl];
                uint4 v4 = hs8[(size_t)r4 * 8 + sl];
                uint4 v5 = hs8[(size_t)r5 * 8 + sl];
                uint4 v6 = hs8[(size_t)r6 * 8 + sl];
                uint4 v7 = hs8[(size_t)r7 * 8 + sl];
                bacc8(lo0, hi0, v0); bacc8(lo1, hi1, v1);
                bacc8(lo2, hi2, v2); bacc8(lo3, hi3, v3);
                bacc8(lo0, hi0, v4); bacc8(lo1, hi1, v5);
                bacc8(lo2, hi2, v6); bacc8(lo3, hi3, v7);
            }
            if (e + 4 <= ee) {
                int r0 = sidx[e + 0], r1 = sidx[e + 1];
                int r2 = sidx[e + 2], r3 = sidx[e + 3];
                uint4 v0 = hs8[(size_t)r0 * 8 + sl];
                uint4 v1 = hs8[(size_t)r1 * 8 + sl];
                uint4 v2 = hs8[(size_t)r2 * 8 + sl];
                uint4 v3 = hs8[(size_t)r3 * 8 + sl];
                bacc8(lo0, hi0, v0); bacc8(lo1, hi1, v1);
                bacc8(lo2, hi2, v2); bacc8(lo3, hi3, v3);
                e += 4;
            }
            for (; e < ee; ++e)
                bacc8(lo0, hi0, hs8[(size_t)sidx[e] * 8 + sl]);
            lo0.x += lo1.x + lo2.x + lo3.x;  hi0.x += hi1.x + hi2.x + hi3.x;
            lo0.y += lo1.y + lo2.y + lo3.y;  hi0.y += hi1.y + hi2.y + hi3.y;
            lo0.z += lo1.z + lo2.z + lo3.z;  hi0.z += hi1.z + hi2.z + hi3.z;
            lo0.w += lo1.w + lo2.w + lo3.w;  hi0.w += hi1.w + hi2.w + hi3.w;
            float4 bb0 = ((const float4*)biasA)[sl * 2];
            float4 bb1 = ((const float4*)biasA)[sl * 2 + 1];
            o0.x = fmaxf(fmaf(lo0.x, d, bb0.x), 0.f);
            o0.y = fmaxf(fmaf(hi0.x, d, bb0.y), 0.f);
            o0.z = fmaxf(fmaf(lo0.y, d, bb0.z), 0.f);
            o0.w = fmaxf(fmaf(hi0.y, d, bb0.w), 0.f);
            o1.x = fmaxf(fmaf(lo0.z, d, bb1.x), 0.f);
            o1.y = fmaxf(fmaf(hi0.z, d, bb1.y), 0.f);
            o1.z = fmaxf(fmaf(lo0.w, d, bb1.z), 0.f);
            o1.w = fmaxf(fmaf(hi0.w, d, bb1.w), 0.f);
        }
        uint4 pk;                                // feature pairs 4sl..4sl+3
        pk.x = pk2(o0.x, o0.y);
        pk.y = pk2(o0.z, o0.w);
        pk.z = pk2(o1.x, o1.y);
        pk.w = pk2(o1.z, o1.w);
        *(uint4*)&htb[n * 36 + sl * 4] = pk;
    }
    __syncthreads();

    // ---- phase B: MFMA, tile-jobs over 8 waves ----
    constexpr int NCT = FINAL ? 3 : 4;           // col tiles (48 padded / 64)
    int wid = tid >> 6, lane = tid & 63;
    int lm = lane & 15, lg = lane >> 4;
    int rt = wid >> 1;
    int ct0 = (wid & 1) * 2;
    int ct1 = (ct0 + 2 < NCT) ? ct0 + 2 : NCT;
    bf16x8 afrag[2];
    #pragma unroll
    for (int kh = 0; kh < 2; ++kh) {
        const unsigned int* p = &htb[(rt * 16 + lm) * 36 + kh * 16 + lg * 4];
        afrag[kh] = __builtin_bit_cast(bf16x8, *(const uint4*)p);
    }
    for (int ct = ct0; ct < ct1; ++ct) {
        f32x4 acc = (f32x4){0.f, 0.f, 0.f, 0.f};
        #pragma unroll
        for (int kh = 0; kh < 2; ++kh) {
            const unsigned short* q = Wt + (size_t)(ct * 16 + lm) * 64 + kh * 32 + lg * 8;
            bf16x8 bfrag = __builtin_bit_cast(bf16x8, *(const uint4*)q);
            acc = __builtin_amdgcn_mfma_f32_16x16x32_bf16(afrag[kh], bfrag, acc, 0, 0, 0);
        }
        if (!FINAL) {
            #pragma unroll
            for (int rg = 0; rg < 4; ++rg) {
                int rloc = rt * 16 + lg * 4 + rg;
                int r = rbase + rloc;
                if (r < NN) {
                    float v = acc[rg] * sdinv[rloc];
                    hsb_out[(size_t)r * NH + ct * 16 + lm] = f2bf(v);
                }
            }
        } else {
            int c = ct * 16 + lm;
            if (c < NC) {
                float bb = biasB[c];
                #pragma unroll
                for (int rg = 0; rg < 4; ++rg) {
                    int rloc = rt * 16 + lg * 4 + rg;
                    int r = rbase + rloc;
                    if (r < NN)
                        f_out[(size_t)r * NC + c] = acc[rg] + bb;
                }
            }
        }
    }
}

// ---------------- launch ----------------

extern "C" void kernel_launch(void* const* d_in, const int* in_sizes, int n_in,
                              void* d_out, int out_size, void* d_ws, size_t ws_size,
                              hipStream_t stream) {
    const float* x  = (const float*)d_in[0];
    const int* ei   = (const int*)d_in[1];      // [2, NE]
    const int* row  = ei;
    const int* col  = ei + NE;
    const float* W1 = (const float*)d_in[2];
    const float* b1 = (const float*)d_in[3];
    const float* W2 = (const float*)d_in[4];
    const float* b2 = (const float*)d_in[5];
    const float* Wc = (const float*)d_in[6];
    const float* bc = (const float*)d_in[7];
    float* out = (float*)d_out;

    char* ws = (char*)d_ws;
    size_t off = 0;
    auto alloc = [&](size_t bytes) {
        void* p = ws + off;
        off = (off + bytes + 255) & ~(size_t)255;
        return p;
    };
    int*   gcnt = (int*)alloc((size_t)NBK * 4);
    int*   offg = (int*)alloc((size_t)NBK * OFFS * 4);
    float* dinv = (float*)alloc((size_t)NN * 4);
    unsigned int* encs = (unsigned int*)alloc((size_t)NBK * CAPB * 4);   // 8 MB
    unsigned short* hsb1 = (unsigned short*)alloc((size_t)NN * NH * 2);  // bf16 table L1
    unsigned short* hsb2 = (unsigned short*)alloc((size_t)NN * NH * 2);  // bf16 table L2
    unsigned short* Wt1  = (unsigned short*)alloc((size_t)64 * 128 * 2); // bf16 W1^T
    unsigned short* Wt2  = (unsigned short*)alloc((size_t)64 * 64 * 2);  // bf16 W2^T
    unsigned short* Wtc  = (unsigned short*)alloc((size_t)48 * 64 * 2);  // bf16 Wc^T padded

    const int GB = (NN + 63) / 64;               // 1563

    prep_wt<<<64, 256, 0, stream>>>(W1, W2, Wc, Wt1, Wt2, Wtc, gcnt);
    // scatter (391 blocks) overlapped with unscaled gemm1 (1563 blocks)
    scatter_gemm1<<<NCHB + GB, 256, 0, stream>>>(row, col, gcnt, encs, x, Wt1, hsb1);
    // node-sort buckets + dinv + scale hsb1 rows in place
    csr_sort<<<NBK, 256, 0, stream>>>(encs, gcnt, offg, dinv, (unsigned int*)hsb1);
    // fused: agg(hsb1) -> relu -> @W2*dinv -> hsb2
    agg_matmul<0><<<NBK * 2, 512, 0, stream>>>(hsb1, (const int*)encs, offg, dinv,
                                               b1, Wt2, nullptr, hsb2, nullptr);
    // fused: agg(hsb2) -> relu -> @Wc + bc -> out
    agg_matmul<1><<<NBK * 2, 512, 0, stream>>>(hsb2, (const int*)encs, offg, dinv,
                                               b2, Wtc, bc, nullptr, out);
}